// Round 9
// baseline (212.640 us; speedup 1.0000x reference)
//
#include <hip/hip_runtime.h>
#include <hip/hip_fp16.h>
#include <math.h>

#define NN    50000
#define NE0   800000
#define NE    850000
#define INDIM 128
#define HID   64
#define OUTD  40

#define NB    391          // ceil(50000/128) buckets of 128 dsts
#define BSH   7            // bucket shift (dst >> 7)
#define BCAP  3072         // per-bucket capacity (max load ~2400)

typedef unsigned short u16;
typedef unsigned char  u8;

__device__ inline u16 f2bf(float f) {
    unsigned u = __float_as_uint(f);
    return (u16)((u + 0x8000u) >> 16);
}
__device__ inline float bf2f(u16 h) {
    return __uint_as_float((unsigned)h << 16);
}

// ---------------------------------------------------------------- CSR build (fixed-capacity buckets)
__global__ __launch_bounds__(512) void k_binit(int* __restrict__ bcur) {
    int i = threadIdx.x;
    if (i < NB) bcur[i] = i * BCAP;
}

// bin edges by bucket: 128 blocks, block reserves per-bucket ranges via global atomics
__global__ __launch_bounds__(256) void k_bin(const int* __restrict__ ei,
                                             int* __restrict__ bcur,
                                             unsigned int* __restrict__ epack) {
    __shared__ int lh[NB];
    __shared__ int lbase[NB];
    const int tid = threadIdx.x;
    const int CH = (NE + 127) / 128;           // 6641
    const int e_begin = blockIdx.x * CH;
    const int e_end = (e_begin + CH < NE) ? e_begin + CH : NE;

    for (int i = tid; i < NB; i += 256) lh[i] = 0;
    __syncthreads();
    for (int e = e_begin + tid; e < e_end; e += 256) {
        int dst = (e < NE0) ? ei[NE0 + e] : (e - NE0);
        atomicAdd(&lh[dst >> BSH], 1);
    }
    __syncthreads();
    for (int i = tid; i < NB; i += 256) {
        int c = lh[i];
        lbase[i] = c ? atomicAdd(&bcur[i], c) : 0;
        lh[i] = 0;
    }
    __syncthreads();
    for (int e = e_begin + tid; e < e_end; e += 256) {
        int src, dst;
        if (e < NE0) { src = ei[e]; dst = ei[NE0 + e]; }
        else         { src = e - NE0; dst = src; }
        int bkt = dst >> BSH;
        int lpos = atomicAdd(&lh[bkt], 1);
        epack[lbase[bkt] + lpos] = (unsigned int)src | ((unsigned int)(dst & 127) << 16);
    }
}

// per-bucket fine CSR + fused layer-1 edge weights -> packed 16B edge records
__global__ __launch_bounds__(256) void k_bucket_csr(
    const int* __restrict__ bcur, const unsigned int* __restrict__ epack,
    const float* __restrict__ asrc1, const float* __restrict__ adst1,
    int* __restrict__ off_s, int* __restrict__ off_e,
    uint4* __restrict__ erec, int* __restrict__ esrc) {
    __shared__ int lh[128];
    __shared__ int lcur[128];
    __shared__ int sblk;
    __shared__ float sadst[512];
    const int tid = threadIdx.x, lane = tid & 63;
    const int b = blockIdx.x;
    const int e0 = b * BCAP;
    const int cnt = bcur[b] - e0;

    for (int i = tid; i < 512; i += 256) {
        int gi = b * 512 + i;
        sadst[i] = (gi < NN * 4) ? adst1[gi] : 0.f;
    }
    if (tid < 128) lh[tid] = 0;
    __syncthreads();
    for (int i = tid; i < cnt; i += 256)
        atomicAdd(&lh[epack[e0 + i] >> 16], 1);
    __syncthreads();

    int v = 0, incl = 0;
    if (tid < 128) {
        v = lh[tid];
        incl = v;
#pragma unroll
        for (int s = 1; s < 64; s <<= 1) {
            int t = __shfl_up(incl, s);
            if (lane >= s) incl += t;
        }
    }
    if (tid == 63) sblk = incl;
    __syncthreads();
    if (tid >= 64 && tid < 128) incl += sblk;
    if (tid < 128) {
        int ex = e0 + incl - v;
        lcur[tid] = ex;
        int gd = b * 128 + tid;
        if (gd < NN) { off_s[gd] = ex; off_e[gd] = ex + v; }
    }
    __syncthreads();

    for (int i = tid; i < cnt; i += 256) {
        unsigned int p = epack[e0 + i];
        int s  = (int)(p & 0xFFFFu);
        int dl = (int)(p >> 16);
        int pos = atomicAdd(&lcur[dl], 1);
        float4 av = *(const float4*)&asrc1[(size_t)s * 4];
        const float* ad = &sadst[dl * 4];
        float e0f = av.x + ad[0], e1f = av.y + ad[1];
        float e2f = av.z + ad[2], e3f = av.w + ad[3];
        e0f = (e0f > 0.f) ? e0f : 0.2f * e0f;
        e1f = (e1f > 0.f) ? e1f : 0.2f * e1f;
        e2f = (e2f > 0.f) ? e2f : 0.2f * e2f;
        e3f = (e3f > 0.f) ? e3f : 0.2f * e3f;
        unsigned lo = (unsigned)f2bf(__expf(e0f)) | ((unsigned)f2bf(__expf(e1f)) << 16);
        unsigned hi = (unsigned)f2bf(__expf(e2f)) | ((unsigned)f2bf(__expf(e3f)) << 16);
        erec[pos] = make_uint4((unsigned)s, lo, hi, (unsigned)dl);
        esrc[pos] = s;
    }
}

// ---------------------------------------------------------------- GEMM1: x(50000x128)@W1(128x64), 4x4 reg tile, fp16 h1 out
__global__ __launch_bounds__(256, 2) void k_gemm1(
    const float* __restrict__ x, const float* __restrict__ W1,
    const float* __restrict__ a_s, const float* __restrict__ a_d,
    __half* __restrict__ h1h, float* __restrict__ asrc1, float* __restrict__ adst1)
{
    __shared__ float Wl[INDIM * HID];      // 32 KB
    __shared__ float xs[64 * 132];         // 33.8 KB, padded stride 132
    const int tid = threadIdx.x;
    const int r0 = blockIdx.x * 64;

    const float4* W4 = (const float4*)W1;
    float4* Wl4 = (float4*)Wl;
#pragma unroll
    for (int i = 0; i < 8; ++i) Wl4[tid + i * 256] = W4[tid + i * 256];

    const float4* x4 = (const float4*)x;
#pragma unroll
    for (int i = 0; i < 8; ++i) {
        int idx = tid + i * 256;           // 0..2047
        int row = idx >> 5;                // 32 float4 per row
        int k4  = idx & 31;
        int nr = r0 + row;
        float4 v = make_float4(0.f, 0.f, 0.f, 0.f);
        if (nr < NN) v = x4[(size_t)nr * 32 + k4];
        *(float4*)&xs[row * 132 + k4 * 4] = v;
    }
    __syncthreads();

    const int rg = tid >> 4;               // 0..15 (4 rows each)
    const int cg = tid & 15;
    const int c4 = cg * 4;
    const float as0 = a_s[c4], as1v = a_s[c4+1], as2v = a_s[c4+2], as3v = a_s[c4+3];
    const float ad0 = a_d[c4], ad1v = a_d[c4+1], ad2v = a_d[c4+2], ad3v = a_d[c4+3];

    float acc[4][4];
#pragma unroll
    for (int i = 0; i < 4; ++i)
#pragma unroll
        for (int j = 0; j < 4; ++j) acc[i][j] = 0.f;

#pragma unroll 4
    for (int k4 = 0; k4 < 32; ++k4) {
        float4 xv[4];
#pragma unroll
        for (int i = 0; i < 4; ++i)
            xv[i] = *(const float4*)&xs[(rg * 4 + i) * 132 + k4 * 4];
        const float* wp = &Wl[(k4 * 4) * HID + c4];
        float4 w0 = *(const float4*)(wp);
        float4 w1 = *(const float4*)(wp + HID);
        float4 w2 = *(const float4*)(wp + 2 * HID);
        float4 w3 = *(const float4*)(wp + 3 * HID);
#pragma unroll
        for (int i = 0; i < 4; ++i) {
            acc[i][0] += xv[i].x * w0.x + xv[i].y * w1.x + xv[i].z * w2.x + xv[i].w * w3.x;
            acc[i][1] += xv[i].x * w0.y + xv[i].y * w1.y + xv[i].z * w2.y + xv[i].w * w3.y;
            acc[i][2] += xv[i].x * w0.z + xv[i].y * w1.z + xv[i].z * w2.z + xv[i].w * w3.z;
            acc[i][3] += xv[i].x * w0.w + xv[i].y * w1.w + xv[i].z * w2.w + xv[i].w * w3.w;
        }
    }

#pragma unroll
    for (int i = 0; i < 4; ++i) {
        const int n = r0 + rg * 4 + i;
        if (n < NN) {
            __half2 ha = __floats2half2_rn(acc[i][0], acc[i][1]);
            __half2 hb = __floats2half2_rn(acc[i][2], acc[i][3]);
            *(__half2*)&h1h[(size_t)n * HID + c4]     = ha;
            *(__half2*)&h1h[(size_t)n * HID + c4 + 2] = hb;
        }
        float ps = acc[i][0] * as0 + acc[i][1] * as1v + acc[i][2] * as2v + acc[i][3] * as3v;
        float pd = acc[i][0] * ad0 + acc[i][1] * ad1v + acc[i][2] * ad2v + acc[i][3] * ad3v;
        ps += __shfl_xor(ps, 1); ps += __shfl_xor(ps, 2);
        pd += __shfl_xor(pd, 1); pd += __shfl_xor(pd, 2);
        if ((cg & 3) == 0 && n < NN) {
            int head = cg >> 2;
            asrc1[n * 4 + head] = ps;
            adst1[n * 4 + head] = pd;
        }
    }
}

// ---------------------------------------------------------------- layer-1 aggregate: packed erec, half2 dims, 2 nodes/wave
__global__ __launch_bounds__(256) void k_fagg1(
    const int* __restrict__ off_s, const int* __restrict__ off_e,
    const uint4* __restrict__ erec,
    const __half* __restrict__ h1h, const float* __restrict__ b1,
    float* __restrict__ hmid)
{
    const int wv = threadIdx.x >> 6, lane = threadIdx.x & 63;
    const int g = lane >> 5, li = lane & 31;      // 2 nodes/wave, 32 lanes each
    const int n = blockIdx.x * 8 + wv * 2 + g;    // grid exact: 6250*8 = 50000
    const int s0 = off_s[n], s1 = off_e[n];
    const int hp = li >> 3;                       // head = dim>>4 = li>>3
    const int last = s1 - 1;

    int maxc = s1 - s0;
    maxc = max(maxc, __shfl_xor(maxc, 32));

    float l = 0.f, a0 = 0.f, a1 = 0.f;
    const char* h1b = (const char*)h1h;
    for (int t = 0; t < maxc; t += 8) {
        uint4 er[8];
        float wx[8];
#pragma unroll
        for (int j = 0; j < 8; ++j) {
            int ix  = s0 + t + j;
            int ixc = (ix < s1) ? ix : last;
            er[j] = erec[ixc];
            unsigned pair = (hp & 2) ? er[j].z : er[j].y;
            unsigned wb = (hp & 1) ? (pair >> 16) : (pair & 0xFFFFu);
            float w = bf2f((u16)wb);
            wx[j] = (ix < s1) ? w : 0.f;
        }
        float2 hx[8];
#pragma unroll
        for (int j = 0; j < 8; ++j) {
            __half2 hv = *(const __half2*)(h1b + ((size_t)er[j].x * 128 + li * 4));
            hx[j] = __half22float2(hv);
        }
#pragma unroll
        for (int j = 0; j < 8; ++j) {
            l  += wx[j];
            a0 += wx[j] * hx[j].x;
            a1 += wx[j] * hx[j].y;
        }
    }
    float2 bv = *(const float2*)&b1[li * 2];
    float rcp = 1.f / l;
    float2 o;
    o.x = fmaxf(a0 * rcp + bv.x, 0.f);
    o.y = fmaxf(a1 * rcp + bv.y, 0.f);
    *(float2*)&hmid[(size_t)n * HID + li * 2] = o;
}

// ---------------------------------------------------------------- GEMM2: hmid(50000x64) @ W2(64x40), fp16 h2 out
__global__ __launch_bounds__(320) void k_gemm2(
    const float* __restrict__ hin, const float* __restrict__ W2,
    const float* __restrict__ a_s, const float* __restrict__ a_d,
    __half* __restrict__ h2h, float* __restrict__ asrc2, float* __restrict__ adst2)
{
    __shared__ float Wl[HID * OUTD];       // 2560 floats
    __shared__ float xs[32 * 68];          // padded stride 68
    __shared__ float s_as[32], s_ad[32];
    const int tid = threadIdx.x;
    const int r0 = blockIdx.x * 32;

    const float4* W4 = (const float4*)W2;  // 640 float4
    float4* Wl4 = (float4*)Wl;
    for (int i = tid; i < 640; i += 320) Wl4[i] = W4[i];
    const float4* x4 = (const float4*)hin;
    for (int i = tid; i < 512; i += 320) {
        int row = i >> 4;                  // 16 float4 per row
        int k4  = i & 15;
        int nr = r0 + row;
        float4 v = make_float4(0.f, 0.f, 0.f, 0.f);
        if (nr < NN) v = x4[(size_t)nr * 16 + k4];
        *(float4*)&xs[row * 68 + k4 * 4] = v;
    }
    if (tid < 32) { s_as[tid] = 0.f; s_ad[tid] = 0.f; }
    __syncthreads();

    const int r  = tid / 10;               // 0..31
    const int cg = tid % 10;
    const int c4 = cg * 4;                 // 0..36
    float a0 = 0.f, a1 = 0.f, a2 = 0.f, a3 = 0.f;
#pragma unroll 4
    for (int k4 = 0; k4 < 16; ++k4) {
        float4 xv = *(const float4*)&xs[r * 68 + k4 * 4];
        const float* wp = &Wl[(k4 * 4) * OUTD + c4];
        float4 w0 = *(const float4*)(wp);
        float4 w1 = *(const float4*)(wp + OUTD);
        float4 w2 = *(const float4*)(wp + 2 * OUTD);
        float4 w3 = *(const float4*)(wp + 3 * OUTD);
        a0 += xv.x * w0.x + xv.y * w1.x + xv.z * w2.x + xv.w * w3.x;
        a1 += xv.x * w0.y + xv.y * w1.y + xv.z * w2.y + xv.w * w3.y;
        a2 += xv.x * w0.z + xv.y * w1.z + xv.z * w2.z + xv.w * w3.z;
        a3 += xv.x * w0.w + xv.y * w1.w + xv.z * w2.w + xv.w * w3.w;
    }
    const int n = r0 + r;
    float ps = a0 * a_s[c4] + a1 * a_s[c4 + 1] + a2 * a_s[c4 + 2] + a3 * a_s[c4 + 3];
    float pd = a0 * a_d[c4] + a1 * a_d[c4 + 1] + a2 * a_d[c4 + 2] + a3 * a_d[c4 + 3];
    atomicAdd(&s_as[r], ps);
    atomicAdd(&s_ad[r], pd);
    if (n < NN) {
        __half2 ha = __floats2half2_rn(a0, a1);
        __half2 hb = __floats2half2_rn(a2, a3);
        *(__half2*)&h2h[(size_t)n * OUTD + c4]     = ha;
        *(__half2*)&h2h[(size_t)n * OUTD + c4 + 2] = hb;
    }
    __syncthreads();
    if (tid < 32) {
        int n2 = r0 + tid;
        if (n2 < NN) { asrc2[n2] = s_as[tid]; adst2[n2] = s_ad[tid]; }
    }
}

// ---------------------------------------------------------------- layer-2 aggregate: inline exp, 3 nodes/wave, LDS log_softmax
__global__ __launch_bounds__(256) void k_fagg2(
    const int* __restrict__ off_s, const int* __restrict__ off_e,
    const int* __restrict__ esrc, const float* __restrict__ asrc2,
    const float* __restrict__ adst2,
    const __half* __restrict__ h2h, const float* __restrict__ b2,
    float* __restrict__ out)
{
    __shared__ float svals[12][OUTD];
    const int wv = threadIdx.x >> 6, lane = threadIdx.x & 63;
    const int g = lane / 20;                       // 0..3 (group 3 idle)
    const int li = lane - g * 20;                  // 0..19
    const bool ga = (g < 3);
    const int n = blockIdx.x * 12 + wv * 3 + (ga ? g : 0);
    const bool valid = ga && (n < NN);
    const int nc = valid ? n : 0;                  // shadow node 0 for idle lanes
    const int s0 = off_s[nc], s1 = off_e[nc];
    const int last = s1 - 1;
    const float adst = adst2[nc];

    int maxc = valid ? (s1 - s0) : 0;
#pragma unroll
    for (int o = 1; o < 64; o <<= 1) maxc = max(maxc, __shfl_xor(maxc, o));

    float l = 0.f, a0 = 0.f, a1 = 0.f;
    const char* h2b = (const char*)h2h;
    for (int t = 0; t < maxc; t += 8) {
        int sx[8];
        int ok[8];
#pragma unroll
        for (int j = 0; j < 8; ++j) {
            int ix  = s0 + t + j;
            ok[j] = (ix < s1);
            int ixc = ok[j] ? ix : last;
            sx[j] = esrc[ixc];
        }
        float ax[8];
#pragma unroll
        for (int j = 0; j < 8; ++j) ax[j] = asrc2[sx[j]];
        float2 hx[8];
#pragma unroll
        for (int j = 0; j < 8; ++j) {
            __half2 hv = *(const __half2*)(h2b + ((size_t)sx[j] * 80 + li * 4));
            hx[j] = __half22float2(hv);
        }
#pragma unroll
        for (int j = 0; j < 8; ++j) {
            float e = ax[j] + adst;
            e = (e > 0.f) ? e : 0.2f * e;
            float w = __expf(e);
            w = ok[j] ? w : 0.f;
            l  += w;
            a0 += w * hx[j].x;
            a1 += w * hx[j].y;
        }
    }
    if (valid) {
        float rcp = 1.f / l;
        float2 bv = *(const float2*)&b2[li * 2];
        svals[wv * 3 + g][li * 2]     = a0 * rcp + bv.x;
        svals[wv * 3 + g][li * 2 + 1] = a1 * rcp + bv.y;
    }
    __syncthreads();

    for (int r = wv; r < 12; r += 4) {
        int n2 = blockIdx.x * 12 + r;
        if (n2 >= NN) continue;
        float v = (lane < OUTD) ? svals[r][lane] : -1e30f;
        float mx = v;
#pragma unroll
        for (int o = 32; o; o >>= 1) mx = fmaxf(mx, __shfl_xor(mx, o));
        float ex = (lane < OUTD) ? __expf(v - mx) : 0.f;
        float sm = ex;
#pragma unroll
        for (int o = 32; o; o >>= 1) sm += __shfl_xor(sm, o);
        if (lane < OUTD) out[(size_t)n2 * OUTD + lane] = v - mx - __logf(sm);
    }
}

// ----------------------------------------------------------------
extern "C" void kernel_launch(void* const* d_in, const int* in_sizes, int n_in,
                              void* d_out, int out_size, void* d_ws, size_t ws_size,
                              hipStream_t stream)
{
    const float* x   = (const float*)d_in[0];
    const int*   ei  = (const int*)  d_in[1];
    const float* W1  = (const float*)d_in[2];
    const float* as1 = (const float*)d_in[3];
    const float* ad1 = (const float*)d_in[4];
    const float* b1  = (const float*)d_in[5];
    const float* W2  = (const float*)d_in[6];
    const float* as2 = (const float*)d_in[7];
    const float* ad2 = (const float*)d_in[8];
    const float* b2  = (const float*)d_in[9];
    float* out = (float*)d_out;

    // flat workspace layout (~54.4 MB of the 268 MB available)
    char* ws = (char*)d_ws;
    __half* h1h   = (__half*)(ws);                        //  6,400,000 B
    float*  hmid  = (float*) (ws +  6400000);             // 12,800,000 B
    __half* h2h   = (__half*)(ws + 19200000);             //  4,000,000 B
    float*  asrc1 = (float*) (ws + 23200000);             //    800,000 B
    float*  adst1 = (float*) (ws + 24000000);             //    800,000 B
    float*  asrc2 = (float*) (ws + 24800000);             //    200,000 B
    float*  adst2 = (float*) (ws + 25000000);             //    200,000 B
    int*    off_s = (int*)   (ws + 25200000);             //    200,000 B
    int*    off_e = (int*)   (ws + 25400000);             //    200,000 B
    unsigned int* epack = (unsigned int*)(ws + 25600000); //  4,804,608 B (NB*BCAP*4)
    uint4*  erec  = (uint4*) (ws + 30404608);             // 19,218,432 B (NB*BCAP*16)
    int*    esrc  = (int*)   (ws + 49623040);             //  4,804,608 B
    int*    bcur  = (int*)   (ws + 54427648);             //      1,564 B

    hipLaunchKernelGGL(k_binit,      dim3(1),    dim3(512), 0, stream, bcur);
    hipLaunchKernelGGL(k_bin,        dim3(128),  dim3(256), 0, stream, ei, bcur, epack);
    hipLaunchKernelGGL(k_gemm1,      dim3(782),  dim3(256), 0, stream, x, W1, as1, ad1, h1h, asrc1, adst1);
    hipLaunchKernelGGL(k_bucket_csr, dim3(NB),   dim3(256), 0, stream, bcur, epack, asrc1, adst1, off_s, off_e, erec, esrc);
    hipLaunchKernelGGL(k_fagg1,      dim3(6250), dim3(256), 0, stream, off_s, off_e, erec, h1h, b1, hmid);
    hipLaunchKernelGGL(k_gemm2,      dim3(1563), dim3(320), 0, stream, hmid, W2, as2, ad2, h2h, asrc2, adst2);
    hipLaunchKernelGGL(k_fagg2,      dim3(4167), dim3(256), 0, stream, off_s, off_e, esrc, asrc2, adst2, h2h, b2, out);
}

// Round 10
// 207.991 us; speedup vs baseline: 1.0224x; 1.0224x over previous
//
#include <hip/hip_runtime.h>
#include <hip/hip_fp16.h>
#include <math.h>

#define NN    50000
#define NE0   800000
#define NE    850000
#define INDIM 128
#define HID   64
#define OUTD  40

#define NB    391          // ceil(50000/128) buckets of 128 dsts
#define BSH   7            // bucket shift (dst >> 7)
#define BCAP  3072         // per-bucket capacity (max load ~2400)

typedef unsigned short u16;
typedef unsigned char  u8;

__device__ inline u16 f2bf(float f) {
    unsigned u = __float_as_uint(f);
    return (u16)((u + 0x8000u) >> 16);
}
__device__ inline float bf2f(u16 h) {
    return __uint_as_float((unsigned)h << 16);
}

// ---------------------------------------------------------------- CSR build (fixed-capacity buckets)
__global__ __launch_bounds__(512) void k_binit(int* __restrict__ bcur) {
    int i = threadIdx.x;
    if (i < NB) bcur[i] = i * BCAP;
}

// bin edges by bucket: single ei read, LDS edge buffer, 256 blocks
__global__ __launch_bounds__(256) void k_bin(const int* __restrict__ ei,
                                             int* __restrict__ bcur,
                                             unsigned int* __restrict__ epack) {
    __shared__ int lh[NB];
    __shared__ int lbase[NB];
    __shared__ unsigned ebuf[3328];
    const int tid = threadIdx.x;
    const int CH = (NE + 255) / 256;           // 3321
    const int e0 = blockIdx.x * CH;
    const int e1 = (e0 + CH < NE) ? e0 + CH : NE;
    const int cnt = e1 - e0;

    for (int i = tid; i < NB; i += 256) lh[i] = 0;
    __syncthreads();
    for (int i = tid; i < cnt; i += 256) {
        int e = e0 + i;
        int src, dst;
        if (e < NE0) { src = ei[e]; dst = ei[NE0 + e]; }
        else         { src = e - NE0; dst = src; }
        int bkt = dst >> BSH;
        ebuf[i] = (unsigned)src | ((unsigned)(dst & 127) << 16) | ((unsigned)bkt << 23);
        atomicAdd(&lh[bkt], 1);
    }
    __syncthreads();
    for (int i = tid; i < NB; i += 256) {
        int c = lh[i];
        lbase[i] = c ? atomicAdd(&bcur[i], c) : 0;
        lh[i] = 0;
    }
    __syncthreads();
    for (int i = tid; i < cnt; i += 256) {
        unsigned rec = ebuf[i];
        int bkt = rec >> 23;
        int lpos = atomicAdd(&lh[bkt], 1);
        epack[lbase[bkt] + lpos] = rec & 0x7FFFFFu;
    }
}

// per-bucket fine CSR + fused layer-1 edge weights (bf16)
__global__ __launch_bounds__(256) void k_bucket_csr(
    const int* __restrict__ bcur, const unsigned int* __restrict__ epack,
    const float* __restrict__ asrc1, const float* __restrict__ adst1,
    int* __restrict__ off_s, int* __restrict__ off_e, int* __restrict__ esrc,
    u8* __restrict__ edst8, u16* __restrict__ w1u) {
    __shared__ int lh[128];
    __shared__ int lcur[128];
    __shared__ int sblk;
    __shared__ float sadst[512];
    const int tid = threadIdx.x, lane = tid & 63;
    const int b = blockIdx.x;
    const int e0 = b * BCAP;
    const int cnt = bcur[b] - e0;

    for (int i = tid; i < 512; i += 256) {
        int gi = b * 512 + i;
        sadst[i] = (gi < NN * 4) ? adst1[gi] : 0.f;
    }
    if (tid < 128) lh[tid] = 0;
    __syncthreads();
    for (int i = tid; i < cnt; i += 256)
        atomicAdd(&lh[epack[e0 + i] >> 16], 1);
    __syncthreads();

    int v = 0, incl = 0;
    if (tid < 128) {
        v = lh[tid];
        incl = v;
#pragma unroll
        for (int s = 1; s < 64; s <<= 1) {
            int t = __shfl_up(incl, s);
            if (lane >= s) incl += t;
        }
    }
    if (tid == 63) sblk = incl;
    __syncthreads();
    if (tid >= 64 && tid < 128) incl += sblk;
    if (tid < 128) {
        int ex = e0 + incl - v;
        lcur[tid] = ex;
        int gd = b * 128 + tid;
        if (gd < NN) { off_s[gd] = ex; off_e[gd] = ex + v; }
    }
    __syncthreads();

    for (int i = tid; i < cnt; i += 256) {
        unsigned int p = epack[e0 + i];
        int s  = (int)(p & 0xFFFFu);
        int dl = (int)(p >> 16);
        int pos = atomicAdd(&lcur[dl], 1);
        esrc[pos]  = s;
        edst8[pos] = (u8)dl;
        float4 av = *(const float4*)&asrc1[(size_t)s * 4];
        const float* ad = &sadst[dl * 4];
        float e0f = av.x + ad[0], e1f = av.y + ad[1];
        float e2f = av.z + ad[2], e3f = av.w + ad[3];
        e0f = (e0f > 0.f) ? e0f : 0.2f * e0f;
        e1f = (e1f > 0.f) ? e1f : 0.2f * e1f;
        e2f = (e2f > 0.f) ? e2f : 0.2f * e2f;
        e3f = (e3f > 0.f) ? e3f : 0.2f * e3f;
        unsigned lo = (unsigned)f2bf(__expf(e0f)) | ((unsigned)f2bf(__expf(e1f)) << 16);
        unsigned hi = (unsigned)f2bf(__expf(e2f)) | ((unsigned)f2bf(__expf(e3f)) << 16);
        *(uint2*)&w1u[(size_t)pos * 4] = make_uint2(lo, hi);
    }
}

// edge-parallel layer-2 weights (after gemm2)
__global__ __launch_bounds__(256) void k_w2(
    const int* __restrict__ bcur, const int* __restrict__ esrc,
    const u8* __restrict__ edst8, const float* __restrict__ asrc2,
    const float* __restrict__ adst2, u16* __restrict__ w2u) {
    __shared__ float sadst[128];
    const int tid = threadIdx.x;
    const int b = blockIdx.x;
    const int e0 = b * BCAP, e1 = bcur[b];
    if (tid < 128) {
        int gd = b * 128 + tid;
        sadst[tid] = (gd < NN) ? adst2[gd] : 0.f;
    }
    __syncthreads();
    for (int i = e0 + tid; i < e1; i += 256) {
        int s = esrc[i];
        float e = asrc2[s] + sadst[edst8[i]];
        e = (e > 0.f) ? e : 0.2f * e;
        w2u[i] = f2bf(__expf(e));
    }
}

// ---------------------------------------------------------------- GEMM1: x(50000x128)@W1(128x64), 4x4 reg tile, fp16 h1 out
__global__ __launch_bounds__(256, 2) void k_gemm1(
    const float* __restrict__ x, const float* __restrict__ W1,
    const float* __restrict__ a_s, const float* __restrict__ a_d,
    __half* __restrict__ h1h, float* __restrict__ asrc1, float* __restrict__ adst1)
{
    __shared__ float Wl[INDIM * HID];      // 32 KB
    __shared__ float xs[64 * 132];         // 33.8 KB, padded stride 132
    const int tid = threadIdx.x;
    const int r0 = blockIdx.x * 64;

    const float4* W4 = (const float4*)W1;
    float4* Wl4 = (float4*)Wl;
#pragma unroll
    for (int i = 0; i < 8; ++i) Wl4[tid + i * 256] = W4[tid + i * 256];

    const float4* x4 = (const float4*)x;
#pragma unroll
    for (int i = 0; i < 8; ++i) {
        int idx = tid + i * 256;           // 0..2047
        int row = idx >> 5;                // 32 float4 per row
        int k4  = idx & 31;
        int nr = r0 + row;
        float4 v = make_float4(0.f, 0.f, 0.f, 0.f);
        if (nr < NN) v = x4[(size_t)nr * 32 + k4];
        *(float4*)&xs[row * 132 + k4 * 4] = v;
    }
    __syncthreads();

    const int rg = tid >> 4;               // 0..15 (4 rows each)
    const int cg = tid & 15;
    const int c4 = cg * 4;
    const float as0 = a_s[c4], as1v = a_s[c4+1], as2v = a_s[c4+2], as3v = a_s[c4+3];
    const float ad0 = a_d[c4], ad1v = a_d[c4+1], ad2v = a_d[c4+2], ad3v = a_d[c4+3];

    float acc[4][4];
#pragma unroll
    for (int i = 0; i < 4; ++i)
#pragma unroll
        for (int j = 0; j < 4; ++j) acc[i][j] = 0.f;

#pragma unroll 4
    for (int k4 = 0; k4 < 32; ++k4) {
        float4 xv[4];
#pragma unroll
        for (int i = 0; i < 4; ++i)
            xv[i] = *(const float4*)&xs[(rg * 4 + i) * 132 + k4 * 4];
        const float* wp = &Wl[(k4 * 4) * HID + c4];
        float4 w0 = *(const float4*)(wp);
        float4 w1 = *(const float4*)(wp + HID);
        float4 w2 = *(const float4*)(wp + 2 * HID);
        float4 w3 = *(const float4*)(wp + 3 * HID);
#pragma unroll
        for (int i = 0; i < 4; ++i) {
            acc[i][0] += xv[i].x * w0.x + xv[i].y * w1.x + xv[i].z * w2.x + xv[i].w * w3.x;
            acc[i][1] += xv[i].x * w0.y + xv[i].y * w1.y + xv[i].z * w2.y + xv[i].w * w3.y;
            acc[i][2] += xv[i].x * w0.z + xv[i].y * w1.z + xv[i].z * w2.z + xv[i].w * w3.z;
            acc[i][3] += xv[i].x * w0.w + xv[i].y * w1.w + xv[i].z * w2.w + xv[i].w * w3.w;
        }
    }

#pragma unroll
    for (int i = 0; i < 4; ++i) {
        const int n = r0 + rg * 4 + i;
        if (n < NN) {
            __half2 ha = __floats2half2_rn(acc[i][0], acc[i][1]);
            __half2 hb = __floats2half2_rn(acc[i][2], acc[i][3]);
            *(__half2*)&h1h[(size_t)n * HID + c4]     = ha;
            *(__half2*)&h1h[(size_t)n * HID + c4 + 2] = hb;
        }
        float ps = acc[i][0] * as0 + acc[i][1] * as1v + acc[i][2] * as2v + acc[i][3] * as3v;
        float pd = acc[i][0] * ad0 + acc[i][1] * ad1v + acc[i][2] * ad2v + acc[i][3] * ad3v;
        ps += __shfl_xor(ps, 1); ps += __shfl_xor(ps, 2);
        pd += __shfl_xor(pd, 1); pd += __shfl_xor(pd, 2);
        if ((cg & 3) == 0 && n < NN) {
            int head = cg >> 2;
            asrc1[n * 4 + head] = ps;
            adst1[n * 4 + head] = pd;
        }
    }
}

// ---------------------------------------------------------------- layer-1 aggregate: 4 nodes/wave, 16 lanes x 4 dims (half4)
__global__ __launch_bounds__(256) void k_fagg1(
    const int* __restrict__ off_s, const int* __restrict__ off_e,
    const int* __restrict__ esrc, const u16* __restrict__ w1u,
    const __half* __restrict__ h1h, const float* __restrict__ b1,
    __half* __restrict__ hmid)
{
    const int wv = threadIdx.x >> 6, lane = threadIdx.x & 63;
    const int g = lane >> 4, li = lane & 15;      // 4 nodes/wave, 16 lanes each
    const int n = blockIdx.x * 16 + wv * 4 + g;   // grid exact: 3125*16 = 50000
    const int s0 = off_s[n], s1 = off_e[n];
    const int hp = li >> 2;                       // head = (li*4)>>4
    const int last = s1 - 1;

    float l = 0.f, a0 = 0.f, a1 = 0.f, a2 = 0.f, a3 = 0.f;
    const char* hb = (const char*)h1h;
    for (int t = s0; t < s1; t += 8) {
        int   sx[8];
        float wx[8];
#pragma unroll
        for (int j = 0; j < 8; ++j) {
            int ix  = t + j;
            int ixc = (ix < s1) ? ix : last;
            sx[j] = esrc[ixc];
            float w = bf2f(w1u[(size_t)ixc * 4 + hp]);
            wx[j] = (ix < s1) ? w : 0.f;
        }
        float2 f0[8], f1[8];
#pragma unroll
        for (int j = 0; j < 8; ++j) {
            uint2 raw = *(const uint2*)(hb + ((size_t)sx[j] * 128 + li * 8));
            f0[j] = __half22float2(*(__half2*)&raw.x);
            f1[j] = __half22float2(*(__half2*)&raw.y);
        }
#pragma unroll
        for (int j = 0; j < 8; ++j) {
            l  += wx[j];
            a0 += wx[j] * f0[j].x;
            a1 += wx[j] * f0[j].y;
            a2 += wx[j] * f1[j].x;
            a3 += wx[j] * f1[j].y;
        }
    }
    float rcp = 1.f / l;
    float4 bv = *(const float4*)&b1[li * 4];
    float o0 = fmaxf(a0 * rcp + bv.x, 0.f);
    float o1 = fmaxf(a1 * rcp + bv.y, 0.f);
    float o2 = fmaxf(a2 * rcp + bv.z, 0.f);
    float o3 = fmaxf(a3 * rcp + bv.w, 0.f);
    __half2 ha = __floats2half2_rn(o0, o1);
    __half2 hc = __floats2half2_rn(o2, o3);
    uint2 st;
    st.x = *(unsigned*)&ha;
    st.y = *(unsigned*)&hc;
    *(uint2*)((char*)hmid + ((size_t)n * 128 + li * 8)) = st;
}

// ---------------------------------------------------------------- GEMM2: hmid_fp16(50000x64) @ W2(64x40), fp16 h2 out
__global__ __launch_bounds__(320) void k_gemm2(
    const __half* __restrict__ hin, const float* __restrict__ W2,
    const float* __restrict__ a_s, const float* __restrict__ a_d,
    __half* __restrict__ h2h, float* __restrict__ asrc2, float* __restrict__ adst2)
{
    __shared__ float Wl[HID * OUTD];       // 2560 floats
    __shared__ float xs[32 * 68];          // padded stride 68
    __shared__ float s_as[32], s_ad[32];
    const int tid = threadIdx.x;
    const int r0 = blockIdx.x * 32;

    const float4* W4 = (const float4*)W2;  // 640 float4
    float4* Wl4 = (float4*)Wl;
    for (int i = tid; i < 640; i += 320) Wl4[i] = W4[i];
    const uint2* x4 = (const uint2*)hin;   // 4 halfs per uint2; 16 per row
    for (int i = tid; i < 512; i += 320) {
        int row = i >> 4;
        int c   = i & 15;
        int nr = r0 + row;
        float4 v = make_float4(0.f, 0.f, 0.f, 0.f);
        if (nr < NN) {
            uint2 raw = x4[(size_t)nr * 16 + c];
            float2 p0 = __half22float2(*(__half2*)&raw.x);
            float2 p1 = __half22float2(*(__half2*)&raw.y);
            v = make_float4(p0.x, p0.y, p1.x, p1.y);
        }
        *(float4*)&xs[row * 68 + c * 4] = v;
    }
    if (tid < 32) { s_as[tid] = 0.f; s_ad[tid] = 0.f; }
    __syncthreads();

    const int r  = tid / 10;               // 0..31
    const int cg = tid % 10;
    const int c4 = cg * 4;                 // 0..36
    float a0 = 0.f, a1 = 0.f, a2 = 0.f, a3 = 0.f;
#pragma unroll 4
    for (int k4 = 0; k4 < 16; ++k4) {
        float4 xv = *(const float4*)&xs[r * 68 + k4 * 4];
        const float* wp = &Wl[(k4 * 4) * OUTD + c4];
        float4 w0 = *(const float4*)(wp);
        float4 w1 = *(const float4*)(wp + OUTD);
        float4 w2 = *(const float4*)(wp + 2 * OUTD);
        float4 w3 = *(const float4*)(wp + 3 * OUTD);
        a0 += xv.x * w0.x + xv.y * w1.x + xv.z * w2.x + xv.w * w3.x;
        a1 += xv.x * w0.y + xv.y * w1.y + xv.z * w2.y + xv.w * w3.y;
        a2 += xv.x * w0.z + xv.y * w1.z + xv.z * w2.z + xv.w * w3.z;
        a3 += xv.x * w0.w + xv.y * w1.w + xv.z * w2.w + xv.w * w3.w;
    }
    const int n = r0 + r;
    float ps = a0 * a_s[c4] + a1 * a_s[c4 + 1] + a2 * a_s[c4 + 2] + a3 * a_s[c4 + 3];
    float pd = a0 * a_d[c4] + a1 * a_d[c4 + 1] + a2 * a_d[c4 + 2] + a3 * a_d[c4 + 3];
    atomicAdd(&s_as[r], ps);
    atomicAdd(&s_ad[r], pd);
    if (n < NN) {
        __half2 ha = __floats2half2_rn(a0, a1);
        __half2 hb = __floats2half2_rn(a2, a3);
        *(__half2*)&h2h[(size_t)n * OUTD + c4]     = ha;
        *(__half2*)&h2h[(size_t)n * OUTD + c4 + 2] = hb;
    }
    __syncthreads();
    if (tid < 32) {
        int n2 = r0 + tid;
        if (n2 < NN) { asrc2[n2] = s_as[tid]; adst2[n2] = s_ad[tid]; }
    }
}

// ---------------------------------------------------------------- layer-2 aggregate: 6 nodes/wave, 10 lanes x 4 dims, LDS log_softmax
__global__ __launch_bounds__(256) void k_fagg2(
    const int* __restrict__ off_s, const int* __restrict__ off_e,
    const int* __restrict__ esrc, const u16* __restrict__ w2u,
    const __half* __restrict__ h2h, const float* __restrict__ b2,
    float* __restrict__ out)
{
    __shared__ float svals[24][OUTD];
    const int wv = threadIdx.x >> 6, lane = threadIdx.x & 63;
    const int g = lane / 10;                       // 0..6 (g==6 idle)
    const int li = lane - g * 10;                  // 0..9
    const bool ga = (g < 6);
    const int n = blockIdx.x * 24 + wv * 6 + (ga ? g : 0);
    const bool valid = ga && (n < NN);
    const int s0 = valid ? off_s[n] : 0;
    const int s1 = valid ? off_e[n] : 0;
    const int last = s1 - 1;

    float l = 0.f, a0 = 0.f, a1 = 0.f, a2 = 0.f, a3 = 0.f;
    const char* hb = (const char*)h2h;
    for (int t = s0; t < s1; t += 8) {
        int   sx[8];
        float wx[8];
#pragma unroll
        for (int j = 0; j < 8; ++j) {
            int ix  = t + j;
            int ixc = (ix < s1) ? ix : last;
            sx[j] = esrc[ixc];
            float w = bf2f(w2u[ixc]);
            wx[j] = (ix < s1) ? w : 0.f;
        }
        float2 f0[8], f1[8];
#pragma unroll
        for (int j = 0; j < 8; ++j) {
            uint2 raw = *(const uint2*)(hb + ((size_t)sx[j] * 80 + li * 8));
            f0[j] = __half22float2(*(__half2*)&raw.x);
            f1[j] = __half22float2(*(__half2*)&raw.y);
        }
#pragma unroll
        for (int j = 0; j < 8; ++j) {
            l  += wx[j];
            a0 += wx[j] * f0[j].x;
            a1 += wx[j] * f0[j].y;
            a2 += wx[j] * f1[j].x;
            a3 += wx[j] * f1[j].y;
        }
    }
    if (valid) {
        float rcp = 1.f / l;
        float4 bv = *(const float4*)&b2[li * 4];
        int r = wv * 6 + g;
        svals[r][li * 4]     = a0 * rcp + bv.x;
        svals[r][li * 4 + 1] = a1 * rcp + bv.y;
        svals[r][li * 4 + 2] = a2 * rcp + bv.z;
        svals[r][li * 4 + 3] = a3 * rcp + bv.w;
    }
    __syncthreads();

    for (int r = wv; r < 24; r += 4) {
        int n2 = blockIdx.x * 24 + r;
        if (n2 >= NN) continue;
        float v = (lane < OUTD) ? svals[r][lane] : -1e30f;
        float mx = v;
#pragma unroll
        for (int o = 32; o; o >>= 1) mx = fmaxf(mx, __shfl_xor(mx, o));
        float ex = (lane < OUTD) ? __expf(v - mx) : 0.f;
        float sm = ex;
#pragma unroll
        for (int o = 32; o; o >>= 1) sm += __shfl_xor(sm, o);
        if (lane < OUTD) out[(size_t)n2 * OUTD + lane] = v - mx - __logf(sm);
    }
}

// ----------------------------------------------------------------
extern "C" void kernel_launch(void* const* d_in, const int* in_sizes, int n_in,
                              void* d_out, int out_size, void* d_ws, size_t ws_size,
                              hipStream_t stream)
{
    const float* x   = (const float*)d_in[0];
    const int*   ei  = (const int*)  d_in[1];
    const float* W1  = (const float*)d_in[2];
    const float* as1 = (const float*)d_in[3];
    const float* ad1 = (const float*)d_in[4];
    const float* b1  = (const float*)d_in[5];
    const float* W2  = (const float*)d_in[6];
    const float* as2 = (const float*)d_in[7];
    const float* ad2 = (const float*)d_in[8];
    const float* b2  = (const float*)d_in[9];
    float* out = (float*)d_out;

    // flat workspace layout (~42 MB of the 268 MB available)
    char* ws = (char*)d_ws;
    __half* h1h   = (__half*)(ws);                        //  6,400,000 B
    __half* hmidh = (__half*)(ws +  6400000);             //  6,400,000 B
    __half* h2h   = (__half*)(ws + 12800000);             //  4,000,000 B
    float*  asrc1 = (float*) (ws + 16800000);             //    800,000 B
    float*  adst1 = (float*) (ws + 17600000);             //    800,000 B
    float*  asrc2 = (float*) (ws + 18400000);             //    200,000 B
    float*  adst2 = (float*) (ws + 18600000);             //    200,000 B
    int*    off_s = (int*)   (ws + 18800000);             //    200,000 B
    int*    off_e = (int*)   (ws + 19000000);             //    200,000 B
    unsigned int* epack = (unsigned int*)(ws + 19200000); //  4,804,608 B (NB*BCAP*4)
    int*    esrc  = (int*)   (ws + 24004608);             //  4,804,608 B
    u8*     edst8 = (u8*)    (ws + 28809216);             //  1,201,152 B
    u16*    w1u   = (u16*)   (ws + 30010368);             //  9,609,216 B
    u16*    w2u   = (u16*)   (ws + 39619584);             //  2,402,304 B
    int*    bcur  = (int*)   (ws + 42021888);             //      1,564 B

    hipLaunchKernelGGL(k_binit,      dim3(1),    dim3(512), 0, stream, bcur);
    hipLaunchKernelGGL(k_bin,        dim3(256),  dim3(256), 0, stream, ei, bcur, epack);
    hipLaunchKernelGGL(k_gemm1,      dim3(782),  dim3(256), 0, stream, x, W1, as1, ad1, h1h, asrc1, adst1);
    hipLaunchKernelGGL(k_bucket_csr, dim3(NB),   dim3(256), 0, stream, bcur, epack, asrc1, adst1, off_s, off_e, esrc, edst8, w1u);
    hipLaunchKernelGGL(k_fagg1,      dim3(3125), dim3(256), 0, stream, off_s, off_e, esrc, w1u, h1h, b1, hmidh);
    hipLaunchKernelGGL(k_gemm2,      dim3(1563), dim3(320), 0, stream, hmidh, W2, as2, ad2, h2h, asrc2, adst2);
    hipLaunchKernelGGL(k_w2,         dim3(NB),   dim3(256), 0, stream, bcur, esrc, edst8, asrc2, adst2, w2u);
    hipLaunchKernelGGL(k_fagg2,      dim3(2084), dim3(256), 0, stream, off_s, off_e, esrc, w2u, h2h, b2, out);
}

// Round 11
// 192.852 us; speedup vs baseline: 1.1026x; 1.0785x over previous
//
#include <hip/hip_runtime.h>
#include <hip/hip_fp16.h>
#include <math.h>

#define NN    50000
#define NE0   800000
#define NE    850000
#define INDIM 128
#define HID   64
#define OUTD  40

#define NB    391          // ceil(50000/128) buckets of 128 dsts
#define BSH   7            // bucket shift (dst >> 7)
#define BCAP  3072         // per-bucket capacity (max load ~2400)

typedef unsigned short u16;

// ---------------------------------------------------------------- bin edges by bucket (bcur pre-inited by k_gemm1)
__global__ __launch_bounds__(256) void k_bin(const int* __restrict__ ei,
                                             int* __restrict__ bcur,
                                             unsigned int* __restrict__ epack) {
    __shared__ int lh[NB];
    __shared__ int lbase[NB];
    __shared__ unsigned ebuf[3328];
    const int tid = threadIdx.x;
    const int CH = (NE + 255) / 256;           // 3321
    const int e0 = blockIdx.x * CH;
    const int e1 = (e0 + CH < NE) ? e0 + CH : NE;
    const int cnt = e1 - e0;

    for (int i = tid; i < NB; i += 256) lh[i] = 0;
    __syncthreads();
    for (int i = tid; i < cnt; i += 256) {
        int e = e0 + i;
        int src, dst;
        if (e < NE0) { src = ei[e]; dst = ei[NE0 + e]; }
        else         { src = e - NE0; dst = src; }
        int bkt = dst >> BSH;
        ebuf[i] = (unsigned)src | ((unsigned)(dst & 127) << 16) | ((unsigned)bkt << 23);
        atomicAdd(&lh[bkt], 1);
    }
    __syncthreads();
    for (int i = tid; i < NB; i += 256) {
        int c = lh[i];
        lbase[i] = c ? atomicAdd(&bcur[i], c) : 0;
        lh[i] = 0;
    }
    __syncthreads();
    for (int i = tid; i < cnt; i += 256) {
        unsigned rec = ebuf[i];
        int bkt = rec >> 23;
        int lpos = atomicAdd(&lh[bkt], 1);
        epack[lbase[bkt] + lpos] = rec & 0x7FFFFFu;
    }
}

// ---------------------------------------------------------------- per-bucket fine CSR (pure: off + esrc only)
__global__ __launch_bounds__(256) void k_bucket_csr(
    const int* __restrict__ bcur, const unsigned int* __restrict__ epack,
    int* __restrict__ off_s, int* __restrict__ off_e, int* __restrict__ esrc) {
    __shared__ int lh[128];
    __shared__ int lcur[128];
    __shared__ int sblk;
    const int tid = threadIdx.x, lane = tid & 63;
    const int b = blockIdx.x;
    const int e0 = b * BCAP;
    const int cnt = bcur[b] - e0;

    if (tid < 128) lh[tid] = 0;
    __syncthreads();
    for (int i = tid; i < cnt; i += 256)
        atomicAdd(&lh[epack[e0 + i] >> 16], 1);
    __syncthreads();

    int v = 0, incl = 0;
    if (tid < 128) {
        v = lh[tid];
        incl = v;
#pragma unroll
        for (int s = 1; s < 64; s <<= 1) {
            int t = __shfl_up(incl, s);
            if (lane >= s) incl += t;
        }
    }
    if (tid == 63) sblk = incl;
    __syncthreads();
    if (tid >= 64 && tid < 128) incl += sblk;
    if (tid < 128) {
        int ex = e0 + incl - v;
        lcur[tid] = ex;
        int gd = b * 128 + tid;
        if (gd < NN) { off_s[gd] = ex; off_e[gd] = ex + v; }
    }
    __syncthreads();

    for (int i = tid; i < cnt; i += 256) {
        unsigned int p = epack[e0 + i];
        int pos = atomicAdd(&lcur[p >> 16], 1);
        esrc[pos] = (int)(p & 0xFFFFu);
    }
}

// ---------------------------------------------------------------- GEMM1: x(50000x128)@W1(128x64), 4x4 reg tile, fp16 h1 out
// also inits bcur (runs first in stream order)
__global__ __launch_bounds__(256, 2) void k_gemm1(
    const float* __restrict__ x, const float* __restrict__ W1,
    const float* __restrict__ a_s, const float* __restrict__ a_d,
    __half* __restrict__ h1h, float* __restrict__ asrc1, float* __restrict__ adst1,
    int* __restrict__ bcur)
{
    __shared__ float Wl[INDIM * HID];      // 32 KB
    __shared__ float xs[64 * 132];         // 33.8 KB, padded stride 132
    const int tid = threadIdx.x;
    const int r0 = blockIdx.x * 64;

    if (blockIdx.x == 0) {
        for (int i = tid; i < NB; i += 256) bcur[i] = i * BCAP;
    }

    const float4* W4 = (const float4*)W1;
    float4* Wl4 = (float4*)Wl;
#pragma unroll
    for (int i = 0; i < 8; ++i) Wl4[tid + i * 256] = W4[tid + i * 256];

    const float4* x4 = (const float4*)x;
#pragma unroll
    for (int i = 0; i < 8; ++i) {
        int idx = tid + i * 256;           // 0..2047
        int row = idx >> 5;                // 32 float4 per row
        int k4  = idx & 31;
        int nr = r0 + row;
        float4 v = make_float4(0.f, 0.f, 0.f, 0.f);
        if (nr < NN) v = x4[(size_t)nr * 32 + k4];
        *(float4*)&xs[row * 132 + k4 * 4] = v;
    }
    __syncthreads();

    const int rg = tid >> 4;               // 0..15 (4 rows each)
    const int cg = tid & 15;
    const int c4 = cg * 4;
    const float as0 = a_s[c4], as1v = a_s[c4+1], as2v = a_s[c4+2], as3v = a_s[c4+3];
    const float ad0 = a_d[c4], ad1v = a_d[c4+1], ad2v = a_d[c4+2], ad3v = a_d[c4+3];

    float acc[4][4];
#pragma unroll
    for (int i = 0; i < 4; ++i)
#pragma unroll
        for (int j = 0; j < 4; ++j) acc[i][j] = 0.f;

#pragma unroll 4
    for (int k4 = 0; k4 < 32; ++k4) {
        float4 xv[4];
#pragma unroll
        for (int i = 0; i < 4; ++i)
            xv[i] = *(const float4*)&xs[(rg * 4 + i) * 132 + k4 * 4];
        const float* wp = &Wl[(k4 * 4) * HID + c4];
        float4 w0 = *(const float4*)(wp);
        float4 w1 = *(const float4*)(wp + HID);
        float4 w2 = *(const float4*)(wp + 2 * HID);
        float4 w3 = *(const float4*)(wp + 3 * HID);
#pragma unroll
        for (int i = 0; i < 4; ++i) {
            acc[i][0] += xv[i].x * w0.x + xv[i].y * w1.x + xv[i].z * w2.x + xv[i].w * w3.x;
            acc[i][1] += xv[i].x * w0.y + xv[i].y * w1.y + xv[i].z * w2.y + xv[i].w * w3.y;
            acc[i][2] += xv[i].x * w0.z + xv[i].y * w1.z + xv[i].z * w2.z + xv[i].w * w3.z;
            acc[i][3] += xv[i].x * w0.w + xv[i].y * w1.w + xv[i].z * w2.w + xv[i].w * w3.w;
        }
    }

#pragma unroll
    for (int i = 0; i < 4; ++i) {
        const int n = r0 + rg * 4 + i;
        if (n < NN) {
            __half2 ha = __floats2half2_rn(acc[i][0], acc[i][1]);
            __half2 hb = __floats2half2_rn(acc[i][2], acc[i][3]);
            *(__half2*)&h1h[(size_t)n * HID + c4]     = ha;
            *(__half2*)&h1h[(size_t)n * HID + c4 + 2] = hb;
        }
        float ps = acc[i][0] * as0 + acc[i][1] * as1v + acc[i][2] * as2v + acc[i][3] * as3v;
        float pd = acc[i][0] * ad0 + acc[i][1] * ad1v + acc[i][2] * ad2v + acc[i][3] * ad3v;
        ps += __shfl_xor(ps, 1); ps += __shfl_xor(ps, 2);
        pd += __shfl_xor(pd, 1); pd += __shfl_xor(pd, 2);
        if ((cg & 3) == 0 && n < NN) {
            int head = cg >> 2;
            asrc1[n * 4 + head] = ps;
            adst1[n * 4 + head] = pd;
        }
    }
}

// ---------------------------------------------------------------- layer-1 aggregate: 4 nodes/wave, 16 lanes x 4 dims, inline exp
__global__ __launch_bounds__(256) void k_fagg1(
    const int* __restrict__ off_s, const int* __restrict__ off_e,
    const int* __restrict__ esrc, const float* __restrict__ asrc1,
    const float* __restrict__ adst1,
    const __half* __restrict__ h1h, const float* __restrict__ b1,
    __half* __restrict__ hmid)
{
    const int wv = threadIdx.x >> 6, lane = threadIdx.x & 63;
    const int g = lane >> 4, li = lane & 15;      // 4 nodes/wave, 16 lanes each
    const int n = blockIdx.x * 16 + wv * 4 + g;   // grid exact: 3125*16 = 50000
    const int s0 = off_s[n], s1 = off_e[n];
    const int hp = li >> 2;                       // head
    const float adst = adst1[n * 4 + hp];
    const int last = s1 - 1;

    float l = 0.f, a0 = 0.f, a1 = 0.f, a2 = 0.f, a3 = 0.f;
    const char* hb = (const char*)h1h;
    for (int t = s0; t < s1; t += 8) {
        int sx[8];
        int ok[8];
#pragma unroll
        for (int j = 0; j < 8; ++j) {
            int ix  = t + j;
            ok[j] = (ix < s1);
            int ixc = ok[j] ? ix : last;
            sx[j] = esrc[ixc];
        }
        float ax[8];
#pragma unroll
        for (int j = 0; j < 8; ++j) ax[j] = asrc1[sx[j] * 4 + hp];
        float2 f0[8], f1[8];
#pragma unroll
        for (int j = 0; j < 8; ++j) {
            uint2 raw = *(const uint2*)(hb + ((size_t)sx[j] * 128 + li * 8));
            f0[j] = __half22float2(*(__half2*)&raw.x);
            f1[j] = __half22float2(*(__half2*)&raw.y);
        }
#pragma unroll
        for (int j = 0; j < 8; ++j) {
            float e = ax[j] + adst;
            e = (e > 0.f) ? e : 0.2f * e;
            float w = __expf(e);
            w = ok[j] ? w : 0.f;
            l  += w;
            a0 += w * f0[j].x;
            a1 += w * f0[j].y;
            a2 += w * f1[j].x;
            a3 += w * f1[j].y;
        }
    }
    float rcp = 1.f / l;
    float4 bv = *(const float4*)&b1[li * 4];
    float o0 = fmaxf(a0 * rcp + bv.x, 0.f);
    float o1 = fmaxf(a1 * rcp + bv.y, 0.f);
    float o2 = fmaxf(a2 * rcp + bv.z, 0.f);
    float o3 = fmaxf(a3 * rcp + bv.w, 0.f);
    __half2 ha = __floats2half2_rn(o0, o1);
    __half2 hc = __floats2half2_rn(o2, o3);
    uint2 st;
    st.x = *(unsigned*)&ha;
    st.y = *(unsigned*)&hc;
    *(uint2*)((char*)hmid + ((size_t)n * 128 + li * 8)) = st;
}

// ---------------------------------------------------------------- GEMM2: hmid_fp16(50000x64) @ W2(64x40), fp16 h2 out
__global__ __launch_bounds__(320) void k_gemm2(
    const __half* __restrict__ hin, const float* __restrict__ W2,
    const float* __restrict__ a_s, const float* __restrict__ a_d,
    __half* __restrict__ h2h, float* __restrict__ asrc2, float* __restrict__ adst2)
{
    __shared__ float Wl[HID * OUTD];       // 2560 floats
    __shared__ float xs[32 * 68];          // padded stride 68
    __shared__ float s_as[32], s_ad[32];
    const int tid = threadIdx.x;
    const int r0 = blockIdx.x * 32;

    const float4* W4 = (const float4*)W2;  // 640 float4
    float4* Wl4 = (float4*)Wl;
    for (int i = tid; i < 640; i += 320) Wl4[i] = W4[i];
    const uint2* x4 = (const uint2*)hin;   // 4 halfs per uint2; 16 per row
    for (int i = tid; i < 512; i += 320) {
        int row = i >> 4;
        int c   = i & 15;
        int nr = r0 + row;
        float4 v = make_float4(0.f, 0.f, 0.f, 0.f);
        if (nr < NN) {
            uint2 raw = x4[(size_t)nr * 16 + c];
            float2 p0 = __half22float2(*(__half2*)&raw.x);
            float2 p1 = __half22float2(*(__half2*)&raw.y);
            v = make_float4(p0.x, p0.y, p1.x, p1.y);
        }
        *(float4*)&xs[row * 68 + c * 4] = v;
    }
    if (tid < 32) { s_as[tid] = 0.f; s_ad[tid] = 0.f; }
    __syncthreads();

    const int r  = tid / 10;               // 0..31
    const int cg = tid % 10;
    const int c4 = cg * 4;                 // 0..36
    float a0 = 0.f, a1 = 0.f, a2 = 0.f, a3 = 0.f;
#pragma unroll 4
    for (int k4 = 0; k4 < 16; ++k4) {
        float4 xv = *(const float4*)&xs[r * 68 + k4 * 4];
        const float* wp = &Wl[(k4 * 4) * OUTD + c4];
        float4 w0 = *(const float4*)(wp);
        float4 w1 = *(const float4*)(wp + OUTD);
        float4 w2 = *(const float4*)(wp + 2 * OUTD);
        float4 w3 = *(const float4*)(wp + 3 * OUTD);
        a0 += xv.x * w0.x + xv.y * w1.x + xv.z * w2.x + xv.w * w3.x;
        a1 += xv.x * w0.y + xv.y * w1.y + xv.z * w2.y + xv.w * w3.y;
        a2 += xv.x * w0.z + xv.y * w1.z + xv.z * w2.z + xv.w * w3.z;
        a3 += xv.x * w0.w + xv.y * w1.w + xv.z * w2.w + xv.w * w3.w;
    }
    const int n = r0 + r;
    float ps = a0 * a_s[c4] + a1 * a_s[c4 + 1] + a2 * a_s[c4 + 2] + a3 * a_s[c4 + 3];
    float pd = a0 * a_d[c4] + a1 * a_d[c4 + 1] + a2 * a_d[c4 + 2] + a3 * a_d[c4 + 3];
    atomicAdd(&s_as[r], ps);
    atomicAdd(&s_ad[r], pd);
    if (n < NN) {
        __half2 ha = __floats2half2_rn(a0, a1);
        __half2 hb = __floats2half2_rn(a2, a3);
        *(__half2*)&h2h[(size_t)n * OUTD + c4]     = ha;
        *(__half2*)&h2h[(size_t)n * OUTD + c4 + 2] = hb;
    }
    __syncthreads();
    if (tid < 32) {
        int n2 = r0 + tid;
        if (n2 < NN) { asrc2[n2] = s_as[tid]; adst2[n2] = s_ad[tid]; }
    }
}

// ---------------------------------------------------------------- layer-2 aggregate: 6 nodes/wave, inline exp, LDS log_softmax
__global__ __launch_bounds__(256) void k_fagg2(
    const int* __restrict__ off_s, const int* __restrict__ off_e,
    const int* __restrict__ esrc, const float* __restrict__ asrc2,
    const float* __restrict__ adst2,
    const __half* __restrict__ h2h, const float* __restrict__ b2,
    float* __restrict__ out)
{
    __shared__ float svals[24][OUTD];
    const int wv = threadIdx.x >> 6, lane = threadIdx.x & 63;
    const int g = lane / 10;                       // 0..6 (g==6 idle)
    const int li = lane - g * 10;                  // 0..9
    const bool ga = (g < 6);
    const int n = blockIdx.x * 24 + wv * 6 + (ga ? g : 0);
    const bool valid = ga && (n < NN);
    const int s0 = valid ? off_s[n] : 0;
    const int s1 = valid ? off_e[n] : 0;
    const float adst = valid ? adst2[n] : 0.f;
    const int last = s1 - 1;

    float l = 0.f, a0 = 0.f, a1 = 0.f, a2 = 0.f, a3 = 0.f;
    const char* hb = (const char*)h2h;
    for (int t = s0; t < s1; t += 8) {
        int sx[8];
        int ok[8];
#pragma unroll
        for (int j = 0; j < 8; ++j) {
            int ix  = t + j;
            ok[j] = (ix < s1);
            int ixc = ok[j] ? ix : last;
            sx[j] = esrc[ixc];
        }
        float ax[8];
#pragma unroll
        for (int j = 0; j < 8; ++j) ax[j] = asrc2[sx[j]];
        float2 f0[8], f1[8];
#pragma unroll
        for (int j = 0; j < 8; ++j) {
            uint2 raw = *(const uint2*)(hb + ((size_t)sx[j] * 80 + li * 8));
            f0[j] = __half22float2(*(__half2*)&raw.x);
            f1[j] = __half22float2(*(__half2*)&raw.y);
        }
#pragma unroll
        for (int j = 0; j < 8; ++j) {
            float e = ax[j] + adst;
            e = (e > 0.f) ? e : 0.2f * e;
            float w = __expf(e);
            w = ok[j] ? w : 0.f;
            l  += w;
            a0 += w * f0[j].x;
            a1 += w * f0[j].y;
            a2 += w * f1[j].x;
            a3 += w * f1[j].y;
        }
    }
    if (valid) {
        float rcp = 1.f / l;
        float4 bv = *(const float4*)&b2[li * 4];
        int r = wv * 6 + g;
        svals[r][li * 4]     = a0 * rcp + bv.x;
        svals[r][li * 4 + 1] = a1 * rcp + bv.y;
        svals[r][li * 4 + 2] = a2 * rcp + bv.z;
        svals[r][li * 4 + 3] = a3 * rcp + bv.w;
    }
    __syncthreads();

    for (int r = wv; r < 24; r += 4) {
        int n2 = blockIdx.x * 24 + r;
        if (n2 >= NN) continue;
        float v = (lane < OUTD) ? svals[r][lane] : -1e30f;
        float mx = v;
#pragma unroll
        for (int o = 32; o; o >>= 1) mx = fmaxf(mx, __shfl_xor(mx, o));
        float ex = (lane < OUTD) ? __expf(v - mx) : 0.f;
        float sm = ex;
#pragma unroll
        for (int o = 32; o; o >>= 1) sm += __shfl_xor(sm, o);
        if (lane < OUTD) out[(size_t)n2 * OUTD + lane] = v - mx - __logf(sm);
    }
}

// ----------------------------------------------------------------
extern "C" void kernel_launch(void* const* d_in, const int* in_sizes, int n_in,
                              void* d_out, int out_size, void* d_ws, size_t ws_size,
                              hipStream_t stream)
{
    const float* x   = (const float*)d_in[0];
    const int*   ei  = (const int*)  d_in[1];
    const float* W1  = (const float*)d_in[2];
    const float* as1 = (const float*)d_in[3];
    const float* ad1 = (const float*)d_in[4];
    const float* b1  = (const float*)d_in[5];
    const float* W2  = (const float*)d_in[6];
    const float* as2 = (const float*)d_in[7];
    const float* ad2 = (const float*)d_in[8];
    const float* b2  = (const float*)d_in[9];
    float* out = (float*)d_out;

    // flat workspace layout (~30 MB of the 268 MB available)
    char* ws = (char*)d_ws;
    __half* h1h   = (__half*)(ws);                        //  6,400,000 B
    __half* hmidh = (__half*)(ws +  6400000);             //  6,400,000 B
    __half* h2h   = (__half*)(ws + 12800000);             //  4,000,000 B
    float*  asrc1 = (float*) (ws + 16800000);             //    800,000 B
    float*  adst1 = (float*) (ws + 17600000);             //    800,000 B
    float*  asrc2 = (float*) (ws + 18400000);             //    200,000 B
    float*  adst2 = (float*) (ws + 18600000);             //    200,000 B
    int*    off_s = (int*)   (ws + 18800000);             //    200,000 B
    int*    off_e = (int*)   (ws + 19000000);             //    200,000 B
    unsigned int* epack = (unsigned int*)(ws + 19200000); //  4,804,608 B (NB*BCAP*4)
    int*    esrc  = (int*)   (ws + 24004608);             //  4,804,608 B
    int*    bcur  = (int*)   (ws + 28809216);             //      1,564 B

    hipLaunchKernelGGL(k_gemm1,      dim3(782),  dim3(256), 0, stream, x, W1, as1, ad1, h1h, asrc1, adst1, bcur);
    hipLaunchKernelGGL(k_bin,        dim3(256),  dim3(256), 0, stream, ei, bcur, epack);
    hipLaunchKernelGGL(k_bucket_csr, dim3(NB),   dim3(256), 0, stream, bcur, epack, off_s, off_e, esrc);
    hipLaunchKernelGGL(k_fagg1,      dim3(3125), dim3(256), 0, stream, off_s, off_e, esrc, asrc1, adst1, h1h, b1, hmidh);
    hipLaunchKernelGGL(k_gemm2,      dim3(1563), dim3(320), 0, stream, hmidh, W2, as2, ad2, h2h, asrc2, adst2);
    hipLaunchKernelGGL(k_fagg2,      dim3(2084), dim3(256), 0, stream, off_s, off_e, esrc, asrc2, adst2, h2h, b2, out);
}